// Round 1
// baseline (136.287 us; speedup 1.0000x reference)
//
#include <hip/hip_runtime.h>

// SSIM over N=32 images of 512x512 fp32, 11x11 Gaussian window (separable),
// zero padding, scalar mean output.
//
// Design: streaming separable conv on 4 planes {x, y, (x+y)^2, (x-y)^2}.
// 128 threads = 128 columns per block; rows streamed with a double-buffered
// LDS row buffer (x,y + 5-col halo); horizontal 11-tap conv with inline
// products; vertical 11-tap conv via register circular buffer (mod-11 made
// static by 11x unroll). SSIM per pixel, clip, local sum, block reduce,
// one float atomicAdd of the partial mean per block.

#define IMG_H 512
#define IMG_W 512
#define NIMG  32
#define TW    128            // columns (threads) per block
#define RROWS 64             // output rows per block
#define NBANDS (IMG_W / TW)  // 4
#define NCHUNK (IMG_H / RROWS) // 8

#define C1F  1.0e-4f         // 0.01^2
#define C2F  9.0e-4f         // 0.03^2
#define EPSF 1.0e-8f

__global__ __launch_bounds__(TW) void ssim_kernel(
    const float* __restrict__ xg, const float* __restrict__ yg,
    const float* __restrict__ wg, float* __restrict__ out)
{
    const int t     = threadIdx.x;
    const int band  = blockIdx.x;   // column band
    const int chunk = blockIdx.y;   // row chunk
    const int img   = blockIdx.z;
    const int c0 = band * TW;
    const int r0 = chunk * RROWS;
    const float* xb = xg + (size_t)img * (IMG_H * IMG_W);
    const float* yb = yg + (size_t)img * (IMG_H * IMG_W);

    __shared__ float gS[11];
    __shared__ float bufX[2][TW + 16];  // [0,138) used: col = c0-5+b
    __shared__ float bufY[2][TW + 16];
    __shared__ float wredS[2];

    // Derive separable 1D kernel: row sums of the (normalized) 2D window.
    if (t < 11) {
        float s = 0.f;
        #pragma unroll
        for (int j = 0; j < 11; ++j) s += wg[t * 11 + j];
        gS[t] = s;
    }
    __syncthreads();
    float g[11];
    #pragma unroll
    for (int k = 0; k < 11; ++k) g[k] = gS[k];

    const int colA = c0 + t;                    // always in [0, IMG_W)
    // threads 0..9 also load the 10 halo columns
    const int  b2     = (t < 5) ? t : (TW + t); // buffer idx for halo
    const int  colB   = c0 - 5 + b2;
    const bool hasB   = (t < 10);
    const bool colBok = hasB && ((unsigned)colB < IMG_W);

    // vertical circular buffers (registers; indices static via 11x unroll)
    float vx[11], vy[11], vs[11], vd[11];

    // preload first input row (r0 - 5)
    {
        int rcur = r0 - 5;
        bool rok = ((unsigned)rcur < IMG_H);
        (void)rok;
    }
    float lxA, lyA, lxB, lyB;
    {
        int rcur = r0 - 5;
        bool rv = ((unsigned)rcur < IMG_H);
        const float* xr = xb + rcur * IMG_W;
        const float* yr = yb + rcur * IMG_W;
        lxA = rv ? xr[colA] : 0.f;
        lyA = rv ? yr[colA] : 0.f;
        lxB = (rv && colBok) ? xr[colB] : 0.f;
        lyB = (rv && colBok) ? yr[colB] : 0.f;
    }

    float acc = 0.f;

    for (int ii = 0; ii < 77; ii += 11) {
        #pragma unroll
        for (int s = 0; s < 11; ++s) {
            const int i = ii + s;               // input-row iteration index
            if (i < RROWS + 10) {               // uniform guard
                const int pb = i & 1;           // double-buffer parity
                bufX[pb][5 + t] = lxA;
                bufY[pb][5 + t] = lyA;
                if (hasB) {
                    bufX[pb][b2] = lxB;
                    bufY[pb][b2] = lyB;
                }
                __syncthreads();

                // prefetch next input row (consumed next iteration)
                {
                    int rn = r0 - 4 + i;
                    bool rv = ((unsigned)rn < IMG_H);
                    const float* xr = xb + rn * IMG_W;
                    const float* yr = yb + rn * IMG_W;
                    lxA = rv ? xr[colA] : 0.f;
                    lyA = rv ? yr[colA] : 0.f;
                    lxB = (rv && colBok) ? xr[colB] : 0.f;
                    lyB = (rv && colBok) ? yr[colB] : 0.f;
                }

                // horizontal 11-tap conv, products inline
                float hx = 0.f, hy = 0.f, hs2 = 0.f, hd2 = 0.f;
                #pragma unroll
                for (int k = 0; k < 11; ++k) {
                    float xv = bufX[pb][t + k];
                    float yv = bufY[pb][t + k];
                    hx = fmaf(g[k], xv, hx);
                    hy = fmaf(g[k], yv, hy);
                    float sv = xv + yv;
                    float dv = xv - yv;
                    hs2 = fmaf(g[k], sv * sv, hs2);
                    hd2 = fmaf(g[k], dv * dv, hd2);
                }
                vx[s] = hx; vy[s] = hy; vs[s] = hs2; vd[s] = hd2;

                if (i >= 10) {                  // output row r0 + i - 10
                    float mx = 0.f, my = 0.f, ms = 0.f, md = 0.f;
                    #pragma unroll
                    for (int j = 0; j < 11; ++j) {
                        const int sl = (s + 1 + j) % 11;  // static
                        mx = fmaf(g[j], vx[sl], mx);
                        my = fmaf(g[j], vy[sl], my);
                        ms = fmaf(g[j], vs[sl], ms);
                        md = fmaf(g[j], vd[sl], md);
                    }
                    float mux2 = mx * mx, muy2 = my * my, muxy = mx * my;
                    float a    = mux2 + muy2;            // mu_x^2 + mu_y^2
                    float esum = 0.5f  * (ms + md);      // Ex2 + Ey2
                    float exy  = 0.25f * (ms - md);      // Exy
                    float sxy  = exy  - muxy;            // sig_xy
                    float ssum = esum - a;               // sig_x2 + sig_y2
                    float num  = fmaf(2.f, muxy, C1F) * fmaf(2.f, sxy, C2F);
                    float den  = (a + C1F) * (ssum + C2F);
                    float v = num * __builtin_amdgcn_rcpf(den + EPSF);
                    v = fminf(fmaxf(v, 0.f), 1.f);
                    acc += v;
                }
            }
        }
    }

    // block reduction: wave shuffle then cross-wave via LDS
    #pragma unroll
    for (int off = 32; off > 0; off >>= 1)
        acc += __shfl_down(acc, off, 64);
    if ((t & 63) == 0) wredS[t >> 6] = acc;
    __syncthreads();
    if (t == 0) {
        float tot = wredS[0] + wredS[1];
        atomicAdd(out, tot * (1.0f / (float)((size_t)NIMG * IMG_H * IMG_W)));
    }
}

extern "C" void kernel_launch(void* const* d_in, const int* in_sizes, int n_in,
                              void* d_out, int out_size, void* d_ws, size_t ws_size,
                              hipStream_t stream) {
    const float* x = (const float*)d_in[0];
    const float* y = (const float*)d_in[1];
    const float* w = (const float*)d_in[2];
    float* out = (float*)d_out;

    // d_out is re-poisoned to 0xAA before every timed launch; zero it first.
    hipMemsetAsync(out, 0, sizeof(float), stream);

    dim3 grid(NBANDS, NCHUNK, NIMG);
    ssim_kernel<<<grid, dim3(TW), 0, stream>>>(x, y, w, out);
}